// Round 1
// baseline (321.343 us; speedup 1.0000x reference)
//
#include <hip/hip_runtime.h>
#include <cstdint>
#include <cstddef>

// ---------------------------------------------------------------------------
// RelativePositionMultiHeadAttention, B=4 L=1024 D=1024 H=16 dk=64
// Key identity: BD[...,L-1:][b,h,i,j] = Q[b,h,i] . Er[4999-j]
//  => scores = Q @ (K + Er_flip)^T / 8  -> plain softmax attention.
// Pipeline: cast->bf16, 3 MFMA GEMMs (Q,K'(+Er),V^T), flash attention, out GEMM.
// ---------------------------------------------------------------------------

typedef __attribute__((ext_vector_type(8))) short short8;   // 8 x bf16 (4 VGPR)
typedef __attribute__((ext_vector_type(4))) float f32x4;    // 4 x f32

#define MFMA_BF16(a, b, c) __builtin_amdgcn_mfma_f32_16x16x32_bf16((a), (b), (c), 0, 0, 0)

constexpr int kB = 4, kL = 1024, kD = 1024, kH = 16, kDk = 64;
constexpr int kBL = kB * kL;   // 4096
constexpr int kMaxLen = 5000;

static __device__ __forceinline__ unsigned short f32_to_bf16(float f) {
  union { float f; uint32_t u; } c; c.f = f;
  uint32_t u = c.u + 0x7fffu + ((c.u >> 16) & 1u);  // RNE
  return (unsigned short)(u >> 16);
}

static __device__ __forceinline__ void gload_lds16(const void* g, void* l) {
  __builtin_amdgcn_global_load_lds(
      (const __attribute__((address_space(1))) void*)g,
      (__attribute__((address_space(3))) void*)l, 16, 0, 0);
}

// ---------------- cast f32 -> bf16, 4 elems/thread ----------------
__global__ void cast_f32_bf16(const float* __restrict__ src,
                              unsigned short* __restrict__ dst, int n4) {
  int i = blockIdx.x * blockDim.x + threadIdx.x;
  if (i >= n4) return;
  float4 v = reinterpret_cast<const float4*>(src)[i];
  ushort4 o;
  o.x = f32_to_bf16(v.x); o.y = f32_to_bf16(v.y);
  o.z = f32_to_bf16(v.z); o.w = f32_to_bf16(v.w);
  reinterpret_cast<ushort4*>(dst)[i] = o;
}

// ---------------- GEMM  C[M,N] = A[M,K] @ B[N,K]^T + bias ----------------
// 128x128 tile, BK=32, 4 waves (2x2 of 64x64), mfma_f32_16x16x32_bf16.
// A-frag: lane holds A[m=lane&15][k=quad*8..+8]; B-frag same over N rows.
// C/D: col = lane&15, row = quad*4 + reg   [verified m89/m91].
enum { MODE_QHEAD = 0, MODE_KHEAD = 1, MODE_VT = 2, MODE_OUT = 3 };

template <int MODE>
__global__ __launch_bounds__(256)
void gemm_bt(const unsigned short* __restrict__ A,   // M x K  bf16
             const unsigned short* __restrict__ Bm,  // N x K  bf16
             const float* __restrict__ bias,         // N      f32
             const float* __restrict__ Er,           // 5000x64 f32 (KHEAD only)
             unsigned short* __restrict__ outb,      // bf16 out (head modes)
             float* __restrict__ outf,               // f32 out  (MODE_OUT)
             int M, int N, int K) {
  __shared__ unsigned short As[128 * 32];
  __shared__ unsigned short Bs[128 * 32];
  const int tid  = threadIdx.x;
  const int lane = tid & 63, wave = tid >> 6;
  const int quad = lane >> 4, l15 = lane & 15;
  const int m0 = blockIdx.y * 128, n0 = blockIdx.x * 128;
  const int wm = (wave >> 1) * 64, wn = (wave & 1) * 64;

  const f32x4 vzero = {0.f, 0.f, 0.f, 0.f};
  f32x4 acc[4][4];
#pragma unroll
  for (int i = 0; i < 4; ++i)
#pragma unroll
    for (int j = 0; j < 4; ++j) acc[i][j] = vzero;

  for (int k0 = 0; k0 < K; k0 += 32) {
    __syncthreads();  // previous tile fully consumed
#pragma unroll
    for (int r = 0; r < 2; ++r) {
      int u = r * 256 + tid;            // 512 x 16B units per buffer
      int row = u >> 2, col = (u & 3) * 8;
      gload_lds16(A  + (size_t)(m0 + row) * K + k0 + col, (char*)As + (size_t)u * 16);
      gload_lds16(Bm + (size_t)(n0 + row) * K + k0 + col, (char*)Bs + (size_t)u * 16);
    }
    __syncthreads();  // drains vmcnt (compiler-inserted) before LDS reads

    short8 af[4], bfv[4];
#pragma unroll
    for (int mt = 0; mt < 4; ++mt)
      af[mt] = *(const short8*)&As[(wm + mt * 16 + l15) * 32 + quad * 8];
#pragma unroll
    for (int nt = 0; nt < 4; ++nt)
      bfv[nt] = *(const short8*)&Bs[(wn + nt * 16 + l15) * 32 + quad * 8];
#pragma unroll
    for (int mt = 0; mt < 4; ++mt)
#pragma unroll
      for (int nt = 0; nt < 4; ++nt)
        acc[mt][nt] = MFMA_BF16(af[mt], bfv[nt], acc[mt][nt]);
  }

  // epilogue
#pragma unroll
  for (int mt = 0; mt < 4; ++mt) {
#pragma unroll
    for (int nt = 0; nt < 4; ++nt) {
#pragma unroll
      for (int r = 0; r < 4; ++r) {
        const int gm = m0 + wm + mt * 16 + quad * 4 + r;  // global row (token)
        const int gn = n0 + wn + nt * 16 + l15;           // global col (feature)
        float v = acc[mt][nt][r] + bias[gn];
        if (MODE == MODE_OUT) {
          outf[(size_t)gm * N + gn] = v;
        } else {
          const int b = gm >> 10, i = gm & 1023;  // L = 1024
          const int h = gn >> 6,  d = gn & 63;    // dk = 64
          if (MODE == MODE_KHEAD) v += Er[(size_t)(4999 - i) * 64 + d];
          size_t idx;
          if (MODE == MODE_VT)
            idx = ((size_t)(b * 16 + h) * 64 + d) * 1024 + i;       // [bh][d][i]
          else
            idx = ((size_t)(b * 16 + h) * 1024 + i) * 64 + d;       // [bh][i][d]
          outb[idx] = f32_to_bf16(v);
        }
      }
    }
  }
}

// ---------------- flash attention ----------------
// grid (64 bh, 16 qblocks), 256 threads. Wave w owns 16 query rows.
// Q,K' head-major [bh][i][64]; V transposed [bh][64][i]; out Ao [b*L][H*64] bf16.
__global__ __launch_bounds__(256)
void attn_kernel(const unsigned short* __restrict__ Q,
                 const unsigned short* __restrict__ Kp,
                 const unsigned short* __restrict__ Vt,
                 unsigned short* __restrict__ Ao) {
  constexpr float kScale = 0.125f * 1.44269504088896340736f;  // log2(e)/sqrt(dk)
  __shared__ unsigned short Plds[4][16 * 72];  // stride 72 keeps b128 reads 16B-aligned
  const int tid  = threadIdx.x;
  const int lane = tid & 63, wave = tid >> 6;
  const int quad = lane >> 4, l15 = lane & 15;
  const int bh = blockIdx.x;   // b*16 + h
  const int qb = blockIdx.y;   // 16 query blocks of 64
  const size_t base = (size_t)bh * kL * 64;
  const int i0 = qb * 64 + wave * 16;

  // Q A-fragments for this wave's 16 rows (dk=64 -> 2 k-steps)
  const unsigned short* qrow = &Q[base + (size_t)(i0 + l15) * 64 + quad * 8];
  short8 qf0 = *(const short8*)qrow;
  short8 qf1 = *(const short8*)(qrow + 32);

  const f32x4 vzero = {0.f, 0.f, 0.f, 0.f};
  f32x4 of[4];
#pragma unroll
  for (int dt = 0; dt < 4; ++dt) of[dt] = vzero;
  float mrow[4], lrow[4];
#pragma unroll
  for (int r = 0; r < 4; ++r) { mrow[r] = -INFINITY; lrow[r] = 0.f; }

  unsigned short* Pw = Plds[wave];

  for (int kb = 0; kb < 16; ++kb) {
    // ---- S = Q @ K'^T for 64 keys ----
    f32x4 sf[4];
#pragma unroll
    for (int nt = 0; nt < 4; ++nt) {
      const unsigned short* kptr =
          &Kp[base + (size_t)(kb * 64 + nt * 16 + l15) * 64 + quad * 8];
      short8 k0 = *(const short8*)kptr;
      short8 k1 = *(const short8*)(kptr + 32);
      sf[nt] = MFMA_BF16(qf0, k0, vzero);
      sf[nt] = MFMA_BF16(qf1, k1, sf[nt]);
    }
    float s[4][4];
#pragma unroll
    for (int nt = 0; nt < 4; ++nt)
#pragma unroll
      for (int r = 0; r < 4; ++r) s[nt][r] = sf[nt][r] * kScale;

    // ---- row max (across 4 col-tiles locally, then 16 lanes) ----
    float mloc[4];
#pragma unroll
    for (int r = 0; r < 4; ++r)
      mloc[r] = fmaxf(fmaxf(s[0][r], s[1][r]), fmaxf(s[2][r], s[3][r]));
#pragma unroll
    for (int mask = 1; mask < 16; mask <<= 1)
#pragma unroll
      for (int r = 0; r < 4; ++r)
        mloc[r] = fmaxf(mloc[r], __shfl_xor(mloc[r], mask));

    float mnew[4], alpha[4];
#pragma unroll
    for (int r = 0; r < 4; ++r) {
      mnew[r] = fmaxf(mrow[r], mloc[r]);
      alpha[r] = exp2f(mrow[r] - mnew[r]);
      mrow[r] = mnew[r];
    }

    // ---- P = exp2(S - m), row sums ----
    float p[4][4], ls[4];
#pragma unroll
    for (int r = 0; r < 4; ++r) ls[r] = 0.f;
#pragma unroll
    for (int nt = 0; nt < 4; ++nt)
#pragma unroll
      for (int r = 0; r < 4; ++r) {
        p[nt][r] = exp2f(s[nt][r] - mnew[r]);
        ls[r] += p[nt][r];
      }
#pragma unroll
    for (int mask = 1; mask < 16; mask <<= 1)
#pragma unroll
      for (int r = 0; r < 4; ++r) ls[r] += __shfl_xor(ls[r], mask);
#pragma unroll
    for (int r = 0; r < 4; ++r) lrow[r] = lrow[r] * alpha[r] + ls[r];
#pragma unroll
    for (int dt = 0; dt < 4; ++dt)
#pragma unroll
      for (int r = 0; r < 4; ++r) of[dt][r] *= alpha[r];

    // ---- P: C-layout -> LDS -> A-layout (wave-private region) ----
#pragma unroll
    for (int nt = 0; nt < 4; ++nt)
#pragma unroll
      for (int r = 0; r < 4; ++r)
        Pw[(quad * 4 + r) * 72 + nt * 16 + l15] = f32_to_bf16(p[nt][r]);
    short8 pf0 = *(const short8*)&Pw[l15 * 72 + quad * 8];
    short8 pf1 = *(const short8*)&Pw[l15 * 72 + 32 + quad * 8];

    // ---- O += P @ V ----
#pragma unroll
    for (int dt = 0; dt < 4; ++dt) {
      const unsigned short* vptr =
          &Vt[(size_t)bh * 64 * kL + (size_t)(dt * 16 + l15) * kL + kb * 64 + quad * 8];
      short8 v0 = *(const short8*)vptr;
      short8 v1 = *(const short8*)(vptr + 32);
      of[dt] = MFMA_BF16(pf0, v0, of[dt]);
      of[dt] = MFMA_BF16(pf1, v1, of[dt]);
    }
  }

  // ---- normalize, write Ao[b*L + i][h*64 + d] (bf16) ----
  const int b = bh >> 4, h = bh & 15;
#pragma unroll
  for (int dt = 0; dt < 4; ++dt)
#pragma unroll
    for (int r = 0; r < 4; ++r) {
      const int ig = i0 + quad * 4 + r;
      float v = of[dt][r] / lrow[r];
      Ao[((size_t)(b * 1024 + ig)) * 1024 + h * 64 + dt * 16 + l15] = f32_to_bf16(v);
    }
}

// ---------------------------------------------------------------------------
extern "C" void kernel_launch(void* const* d_in, const int* in_sizes, int n_in,
                              void* d_out, int out_size, void* d_ws, size_t ws_size,
                              hipStream_t stream) {
  const float* x   = (const float*)d_in[0];
  const float* W_q = (const float*)d_in[1];
  const float* b_q = (const float*)d_in[2];
  const float* W_k = (const float*)d_in[3];
  const float* b_k = (const float*)d_in[4];
  const float* W_v = (const float*)d_in[5];
  const float* b_v = (const float*)d_in[6];
  const float* W_o = (const float*)d_in[7];
  const float* b_o = (const float*)d_in[8];
  const float* Er  = (const float*)d_in[9];
  float* out = (float*)d_out;

  char* ws = (char*)d_ws;
  unsigned short* xb  = (unsigned short*)(ws + (size_t)0);          // 8 MB
  unsigned short* Wqb = (unsigned short*)(ws + ((size_t)8  << 20)); // 2 MB
  unsigned short* Wkb = (unsigned short*)(ws + ((size_t)10 << 20));
  unsigned short* Wvb = (unsigned short*)(ws + ((size_t)12 << 20));
  unsigned short* Wob = (unsigned short*)(ws + ((size_t)14 << 20));
  unsigned short* Qh  = (unsigned short*)(ws + ((size_t)16 << 20)); // 8 MB [bh][i][d]
  unsigned short* Kh  = (unsigned short*)(ws + ((size_t)24 << 20)); // 8 MB [bh][i][d]
  unsigned short* Vth = (unsigned short*)(ws + ((size_t)32 << 20)); // 8 MB [bh][d][i]
  unsigned short* Aoh = (unsigned short*)(ws + ((size_t)40 << 20)); // 8 MB [b*L][D]

  // casts
  cast_f32_bf16<<<(kBL * kD / 4) / 256, 256, 0, stream>>>(x, xb, kBL * kD / 4);
  cast_f32_bf16<<<(kD * kD / 4) / 256, 256, 0, stream>>>(W_q, Wqb, kD * kD / 4);
  cast_f32_bf16<<<(kD * kD / 4) / 256, 256, 0, stream>>>(W_k, Wkb, kD * kD / 4);
  cast_f32_bf16<<<(kD * kD / 4) / 256, 256, 0, stream>>>(W_v, Wvb, kD * kD / 4);
  cast_f32_bf16<<<(kD * kD / 4) / 256, 256, 0, stream>>>(W_o, Wob, kD * kD / 4);

  dim3 grid(kD / 128, kBL / 128), blk(256);  // (8, 32)
  gemm_bt<MODE_QHEAD><<<grid, blk, 0, stream>>>(xb, Wqb, b_q, nullptr, Qh, nullptr, kBL, kD, kD);
  gemm_bt<MODE_KHEAD><<<grid, blk, 0, stream>>>(xb, Wkb, b_k, Er,      Kh, nullptr, kBL, kD, kD);
  gemm_bt<MODE_VT>   <<<grid, blk, 0, stream>>>(xb, Wvb, b_v, nullptr, Vth, nullptr, kBL, kD, kD);

  attn_kernel<<<dim3(kB * kH, kL / 64), 256, 0, stream>>>(Qh, Kh, Vth, Aoh);

  gemm_bt<MODE_OUT><<<grid, blk, 0, stream>>>(Aoh, Wob, b_o, nullptr, nullptr, out, kBL, kD, kD);
}

// Round 2
// 284.539 us; speedup vs baseline: 1.1293x; 1.1293x over previous
//
#include <hip/hip_runtime.h>
#include <cstdint>
#include <cstddef>

// ---------------------------------------------------------------------------
// RelativePositionMultiHeadAttention, B=4 L=1024 D=1024 H=16 dk=64
// Identity: BD[...,L-1:][b,h,i,j] = Q[b,h,i] . Er[4999-j]
//  => scores = Q @ (K + Er_flip)^T / 8  -> plain softmax attention.
// R2: no-max softmax (exp2 never overflows; global shift cancels in O/l),
//     scale folded into Q epilogue, fused QKV GEMM, single cast kernel.
// ---------------------------------------------------------------------------

typedef __attribute__((ext_vector_type(8))) short short8;   // 8 x bf16 (4 VGPR)
typedef __attribute__((ext_vector_type(4))) float f32x4;    // 4 x f32

#define MFMA_BF16(a, b, c) __builtin_amdgcn_mfma_f32_16x16x32_bf16((a), (b), (c), 0, 0, 0)

constexpr int kB = 4, kL = 1024, kD = 1024, kH = 16;
constexpr int kBL = kB * kL;   // 4096
constexpr float kScale = 0.125f * 1.44269504088896340736f;  // log2(e)/sqrt(dk)

static __device__ __forceinline__ unsigned short f32_to_bf16(float f) {
  union { float f; uint32_t u; } c; c.f = f;
  uint32_t u = c.u + 0x7fffu + ((c.u >> 16) & 1u);  // RNE
  return (unsigned short)(u >> 16);
}

static __device__ __forceinline__ void gload_lds16(const void* g, void* l) {
  __builtin_amdgcn_global_load_lds(
      (const __attribute__((address_space(1))) void*)g,
      (__attribute__((address_space(3))) void*)l, 16, 0, 0);
}

// ---------------- single fused cast: x, Wq, Wk, Wv -> Wcat, Wo ----------------
// unit = 4 floats. x: 1048576 units; each W: 262144 units; total 2097152.
__global__ __launch_bounds__(256)
void cast_all(const float* __restrict__ x,  const float* __restrict__ Wq,
              const float* __restrict__ Wk, const float* __restrict__ Wv,
              const float* __restrict__ Wo,
              unsigned short* __restrict__ xb, unsigned short* __restrict__ Wcat,
              unsigned short* __restrict__ Wob) {
  int i = blockIdx.x * blockDim.x + threadIdx.x;
  const float* src;
  ushort4* dst;
  int off;
  if (i < 1048576) {
    src = x; dst = reinterpret_cast<ushort4*>(xb); off = i;
  } else {
    int j = i - 1048576;
    int seg = j >> 18;          // 0..3
    off = j & 262143;
    if (seg == 0)      { src = Wq; dst = reinterpret_cast<ushort4*>(Wcat); }
    else if (seg == 1) { src = Wk; dst = reinterpret_cast<ushort4*>(Wcat) + 262144; }
    else if (seg == 2) { src = Wv; dst = reinterpret_cast<ushort4*>(Wcat) + 524288; }
    else               { src = Wo; dst = reinterpret_cast<ushort4*>(Wob); }
  }
  float4 v = reinterpret_cast<const float4*>(src)[off];
  ushort4 o;
  o.x = f32_to_bf16(v.x); o.y = f32_to_bf16(v.y);
  o.z = f32_to_bf16(v.z); o.w = f32_to_bf16(v.w);
  dst[off] = o;
}

// ---------------- GEMM  C[M,N] = A[M,K] @ B[N,K]^T + bias ----------------
// 128x128 tile, BK=32, 4 waves (2x2 of 64x64), mfma_f32_16x16x32_bf16.
// C/D: col = lane&15, row = quad*4 + reg.
enum { MODE_QKV = 0, MODE_OUT = 1 };

template <int MODE>
__global__ __launch_bounds__(256)
void gemm_bt(const unsigned short* __restrict__ A,   // M x K  bf16
             const unsigned short* __restrict__ Bm,  // N x K  bf16
             const float* __restrict__ bq, const float* __restrict__ bk,
             const float* __restrict__ bv,
             const float* __restrict__ Er,           // 5000x64 f32
             unsigned short* __restrict__ Qh, unsigned short* __restrict__ Kh,
             unsigned short* __restrict__ Vth,
             float* __restrict__ outf,               // f32 out (MODE_OUT)
             int N, int K) {
  __shared__ unsigned short As[128 * 32];
  __shared__ unsigned short Bs[128 * 32];
  const int tid  = threadIdx.x;
  const int lane = tid & 63, wave = tid >> 6;
  const int quad = lane >> 4, l15 = lane & 15;
  const int m0 = blockIdx.y * 128, n0 = blockIdx.x * 128;
  const int wm = (wave >> 1) * 64, wn = (wave & 1) * 64;

  const f32x4 vzero = {0.f, 0.f, 0.f, 0.f};
  f32x4 acc[4][4];
#pragma unroll
  for (int i = 0; i < 4; ++i)
#pragma unroll
    for (int j = 0; j < 4; ++j) acc[i][j] = vzero;

  for (int k0 = 0; k0 < K; k0 += 32) {
    __syncthreads();
#pragma unroll
    for (int r = 0; r < 2; ++r) {
      int u = r * 256 + tid;            // 512 x 16B units per buffer
      int row = u >> 2, col = (u & 3) * 8;
      gload_lds16(A  + (size_t)(m0 + row) * K + k0 + col, (char*)As + (size_t)u * 16);
      gload_lds16(Bm + (size_t)(n0 + row) * K + k0 + col, (char*)Bs + (size_t)u * 16);
    }
    __syncthreads();

    short8 af[4], bfv[4];
#pragma unroll
    for (int mt = 0; mt < 4; ++mt)
      af[mt] = *(const short8*)&As[(wm + mt * 16 + l15) * 32 + quad * 8];
#pragma unroll
    for (int nt = 0; nt < 4; ++nt)
      bfv[nt] = *(const short8*)&Bs[(wn + nt * 16 + l15) * 32 + quad * 8];
#pragma unroll
    for (int mt = 0; mt < 4; ++mt)
#pragma unroll
      for (int nt = 0; nt < 4; ++nt)
        acc[mt][nt] = MFMA_BF16(af[mt], bfv[nt], acc[mt][nt]);
  }

  // epilogue
#pragma unroll
  for (int mt = 0; mt < 4; ++mt) {
#pragma unroll
    for (int nt = 0; nt < 4; ++nt) {
#pragma unroll
      for (int r = 0; r < 4; ++r) {
        const int gm = m0 + wm + mt * 16 + quad * 4 + r;  // token
        const int gn = n0 + wn + nt * 16 + l15;           // feature (or 3*D)
        float v = acc[mt][nt][r];
        if (MODE == MODE_OUT) {
          outf[(size_t)gm * 1024 + gn] = v + bq[gn];
        } else {
          const int wsel = gn >> 10;      // 0=Q 1=K 2=V
          const int n = gn & 1023;
          const int h = n >> 6, d = n & 63;
          const int b = gm >> 10, i = gm & 1023;
          const size_t bh = (size_t)(b * 16 + h);
          if (wsel == 0) {
            v = (v + bq[n]) * kScale;     // fold softmax scale into Q
            Qh[(bh * 1024 + i) * 64 + d] = f32_to_bf16(v);
          } else if (wsel == 1) {
            v = v + bk[n] + Er[(size_t)(4999 - i) * 64 + d];
            Kh[(bh * 1024 + i) * 64 + d] = f32_to_bf16(v);
          } else {
            v = v + bv[n];
            Vth[(bh * 64 + d) * 1024 + i] = f32_to_bf16(v);
          }
        }
      }
    }
  }
}

// ---------------- flash attention, no-max softmax ----------------
// grid (64 bh, 16 qblocks), 256 threads. Wave w owns 16 query rows.
// Q pre-scaled by log2(e)/8. P = exp2(S) directly (|S|<~9 bits of exponent:
// safe in f32/bf16); the usual max-shift cancels in O/l.
__global__ __launch_bounds__(256)
void attn_kernel(const unsigned short* __restrict__ Q,
                 const unsigned short* __restrict__ Kp,
                 const unsigned short* __restrict__ Vt,
                 unsigned short* __restrict__ Ao) {
  __shared__ unsigned short Plds[4][16 * 72];
  const int tid  = threadIdx.x;
  const int lane = tid & 63, wave = tid >> 6;
  const int quad = lane >> 4, l15 = lane & 15;
  const int bh = blockIdx.x;   // b*16 + h
  const int qb = blockIdx.y;
  const size_t base = (size_t)bh * kL * 64;
  const int i0 = qb * 64 + wave * 16;

  const unsigned short* qrow = &Q[base + (size_t)(i0 + l15) * 64 + quad * 8];
  short8 qf0 = *(const short8*)qrow;
  short8 qf1 = *(const short8*)(qrow + 32);

  const f32x4 vzero = {0.f, 0.f, 0.f, 0.f};
  f32x4 of[4];
#pragma unroll
  for (int dt = 0; dt < 4; ++dt) of[dt] = vzero;
  float lsum[4] = {0.f, 0.f, 0.f, 0.f};   // per-lane partial row sums

  unsigned short* Pw = Plds[wave];
  const unsigned short* Vbase = &Vt[(size_t)bh * 64 * kL];

  for (int kb = 0; kb < 16; ++kb) {
    // ---- S = Q @ K'^T (scale pre-folded into Q) ----
    f32x4 sf[4];
#pragma unroll
    for (int nt = 0; nt < 4; ++nt) {
      const unsigned short* kptr =
          &Kp[base + (size_t)(kb * 64 + nt * 16 + l15) * 64 + quad * 8];
      short8 k0 = *(const short8*)kptr;
      short8 k1 = *(const short8*)(kptr + 32);
      sf[nt] = MFMA_BF16(qf0, k0, vzero);
      sf[nt] = MFMA_BF16(qf1, k1, sf[nt]);
    }

    // ---- P = exp2(S); per-lane partial row sums; LDS transpose ----
#pragma unroll
    for (int nt = 0; nt < 4; ++nt)
#pragma unroll
      for (int r = 0; r < 4; ++r) {
        float p = __builtin_amdgcn_exp2f(sf[nt][r]);
        lsum[r] += p;
        Pw[(quad * 4 + r) * 72 + nt * 16 + l15] = f32_to_bf16(p);
      }
    short8 pf0 = *(const short8*)&Pw[l15 * 72 + quad * 8];
    short8 pf1 = *(const short8*)&Pw[l15 * 72 + 32 + quad * 8];

    // ---- O += P @ V ----
#pragma unroll
    for (int dt = 0; dt < 4; ++dt) {
      const unsigned short* vptr =
          Vbase + (size_t)(dt * 16 + l15) * kL + kb * 64 + quad * 8;
      short8 v0 = *(const short8*)vptr;
      short8 v1 = *(const short8*)(vptr + 32);
      of[dt] = MFMA_BF16(pf0, v0, of[dt]);
      of[dt] = MFMA_BF16(pf1, v1, of[dt]);
    }
  }

  // ---- finish row sums (l15 lanes only; quad bits untouched by mask<16) ----
#pragma unroll
  for (int mask = 1; mask < 16; mask <<= 1)
#pragma unroll
    for (int r = 0; r < 4; ++r) lsum[r] += __shfl_xor(lsum[r], mask);
  float rl[4];
#pragma unroll
  for (int r = 0; r < 4; ++r) rl[r] = __builtin_amdgcn_rcpf(lsum[r]);

  // ---- write Ao[b*L + i][h*64 + d] (bf16) ----
  const int b = bh >> 4, h = bh & 15;
#pragma unroll
  for (int dt = 0; dt < 4; ++dt)
#pragma unroll
    for (int r = 0; r < 4; ++r) {
      const int ig = i0 + quad * 4 + r;
      float v = of[dt][r] * rl[r];
      Ao[((size_t)(b * 1024 + ig)) * 1024 + h * 64 + dt * 16 + l15] = f32_to_bf16(v);
    }
}

// ---------------------------------------------------------------------------
extern "C" void kernel_launch(void* const* d_in, const int* in_sizes, int n_in,
                              void* d_out, int out_size, void* d_ws, size_t ws_size,
                              hipStream_t stream) {
  const float* x   = (const float*)d_in[0];
  const float* W_q = (const float*)d_in[1];
  const float* b_q = (const float*)d_in[2];
  const float* W_k = (const float*)d_in[3];
  const float* b_k = (const float*)d_in[4];
  const float* W_v = (const float*)d_in[5];
  const float* b_v = (const float*)d_in[6];
  const float* W_o = (const float*)d_in[7];
  const float* b_o = (const float*)d_in[8];
  const float* Er  = (const float*)d_in[9];
  float* out = (float*)d_out;

  char* ws = (char*)d_ws;
  unsigned short* xb   = (unsigned short*)(ws + (size_t)0);          // 8 MB
  unsigned short* Wcat = (unsigned short*)(ws + ((size_t)8  << 20)); // 6 MB (Wq|Wk|Wv)
  unsigned short* Wob  = (unsigned short*)(ws + ((size_t)14 << 20)); // 2 MB
  unsigned short* Qh   = (unsigned short*)(ws + ((size_t)16 << 20)); // 8 MB [bh][i][d]
  unsigned short* Kh   = (unsigned short*)(ws + ((size_t)24 << 20)); // 8 MB [bh][i][d]
  unsigned short* Vth  = (unsigned short*)(ws + ((size_t)32 << 20)); // 8 MB [bh][d][i]
  unsigned short* Aoh  = (unsigned short*)(ws + ((size_t)40 << 20)); // 8 MB [b*L][D]

  cast_all<<<8192, 256, 0, stream>>>(x, W_q, W_k, W_v, W_o, xb, Wcat, Wob);

  // fused QKV projection: N = 3072 -> 24 x 32 = 768 blocks (3 blocks/CU)
  gemm_bt<MODE_QKV><<<dim3(24, 32), 256, 0, stream>>>(
      xb, Wcat, b_q, b_k, b_v, Er, Qh, Kh, Vth, nullptr, 3072, kD);

  attn_kernel<<<dim3(kB * kH, kL / 64), 256, 0, stream>>>(Qh, Kh, Vth, Aoh);

  gemm_bt<MODE_OUT><<<dim3(8, 32), 256, 0, stream>>>(
      Aoh, Wob, b_o, nullptr, nullptr, nullptr, nullptr, nullptr, nullptr, out, 1024, kD);
}

// Round 4
// 191.267 us; speedup vs baseline: 1.6801x; 1.4877x over previous
//
#include <hip/hip_runtime.h>
#include <cstdint>
#include <cstddef>

// ---------------------------------------------------------------------------
// RelativePositionMultiHeadAttention, B=4 L=1024 D=1024 H=16 dk=64
// Identity: BD[...,L-1:][b,h,i,j] = Q[b,h,i] . Er[4999-j]
//  => scores = Q @ (K + Er_flip)^T / 8  -> plain softmax attention.
// R4: fix gemm_out staging undercount (A needs 512 16B units, B 256; R3
//     loaded 256/128 -> uninit LDS into MFMA). Attention same as R3.
// ---------------------------------------------------------------------------

typedef __attribute__((ext_vector_type(8))) short short8;   // 8 x bf16 (4 VGPR)
typedef __attribute__((ext_vector_type(4))) float f32x4;    // 4 x f32

#define MFMA_BF16(a, b, c) __builtin_amdgcn_mfma_f32_16x16x32_bf16((a), (b), (c), 0, 0, 0)

constexpr int kB = 4, kL = 1024, kD = 1024, kH = 16;
constexpr int kBL = kB * kL;   // 4096
constexpr float kScale = 0.125f * 1.44269504088896340736f;  // log2(e)/sqrt(dk)

static __device__ __forceinline__ unsigned short f32_to_bf16(float f) {
  union { float f; uint32_t u; } c; c.f = f;
  uint32_t u = c.u + 0x7fffu + ((c.u >> 16) & 1u);  // RNE
  return (unsigned short)(u >> 16);
}

static __device__ __forceinline__ void gload_lds16(const void* g, void* l) {
  __builtin_amdgcn_global_load_lds(
      (const __attribute__((address_space(1))) void*)g,
      (__attribute__((address_space(3))) void*)l, 16, 0, 0);
}

// ---------------- single fused cast: x, Wq, Wk, Wv, Wo -> bf16 ----------------
__global__ __launch_bounds__(256)
void cast_all(const float* __restrict__ x,  const float* __restrict__ Wq,
              const float* __restrict__ Wk, const float* __restrict__ Wv,
              const float* __restrict__ Wo,
              unsigned short* __restrict__ xb, unsigned short* __restrict__ Wcat,
              unsigned short* __restrict__ Wob) {
  int i = blockIdx.x * blockDim.x + threadIdx.x;
  const float* src;
  ushort4* dst;
  int off;
  if (i < 1048576) {
    src = x; dst = reinterpret_cast<ushort4*>(xb); off = i;
  } else {
    int j = i - 1048576;
    int seg = j >> 18;          // 0..3
    off = j & 262143;
    if (seg == 0)      { src = Wq; dst = reinterpret_cast<ushort4*>(Wcat); }
    else if (seg == 1) { src = Wk; dst = reinterpret_cast<ushort4*>(Wcat) + 262144; }
    else if (seg == 2) { src = Wv; dst = reinterpret_cast<ushort4*>(Wcat) + 524288; }
    else               { src = Wo; dst = reinterpret_cast<ushort4*>(Wob); }
  }
  float4 v = reinterpret_cast<const float4*>(src)[off];
  ushort4 o;
  o.x = f32_to_bf16(v.x); o.y = f32_to_bf16(v.y);
  o.z = f32_to_bf16(v.z); o.w = f32_to_bf16(v.w);
  dst[off] = o;
}

// ---------------- fused QKV GEMM  [4096 x 3072] = xb @ Wcat^T ----------------
// 128x128 tile, BK=32, 4 waves (2x2 of 64x64).  C/D: col=lane&15, row=quad*4+reg.
__global__ __launch_bounds__(256)
void gemm_qkv(const unsigned short* __restrict__ A,   // 4096 x 1024 bf16
              const unsigned short* __restrict__ Bm,  // 3072 x 1024 bf16
              const float* __restrict__ bq, const float* __restrict__ bk,
              const float* __restrict__ bv,
              const float* __restrict__ Er,           // 5000x64 f32
              unsigned short* __restrict__ Qh, unsigned short* __restrict__ Kh,
              unsigned short* __restrict__ Vth) {
  __shared__ unsigned short As[128 * 32];
  __shared__ unsigned short Bs[128 * 32];
  const int tid  = threadIdx.x;
  const int lane = tid & 63, wave = tid >> 6;
  const int quad = lane >> 4, l15 = lane & 15;
  const int m0 = blockIdx.y * 128, n0 = blockIdx.x * 128;
  const int wm = (wave >> 1) * 64, wn = (wave & 1) * 64;
  const int K = 1024;

  const f32x4 vzero = {0.f, 0.f, 0.f, 0.f};
  f32x4 acc[4][4];
#pragma unroll
  for (int i = 0; i < 4; ++i)
#pragma unroll
    for (int j = 0; j < 4; ++j) acc[i][j] = vzero;

  for (int k0 = 0; k0 < K; k0 += 32) {
    __syncthreads();
#pragma unroll
    for (int r = 0; r < 2; ++r) {
      int u = r * 256 + tid;            // 512 x 16B units per buffer
      int row = u >> 2, col = (u & 3) * 8;
      gload_lds16(A  + (size_t)(m0 + row) * K + k0 + col, (char*)As + (size_t)u * 16);
      gload_lds16(Bm + (size_t)(n0 + row) * K + k0 + col, (char*)Bs + (size_t)u * 16);
    }
    __syncthreads();

    short8 af[4], bfv[4];
#pragma unroll
    for (int mt = 0; mt < 4; ++mt)
      af[mt] = *(const short8*)&As[(wm + mt * 16 + l15) * 32 + quad * 8];
#pragma unroll
    for (int nt = 0; nt < 4; ++nt)
      bfv[nt] = *(const short8*)&Bs[(wn + nt * 16 + l15) * 32 + quad * 8];
#pragma unroll
    for (int mt = 0; mt < 4; ++mt)
#pragma unroll
      for (int nt = 0; nt < 4; ++nt)
        acc[mt][nt] = MFMA_BF16(af[mt], bfv[nt], acc[mt][nt]);
  }

#pragma unroll
  for (int mt = 0; mt < 4; ++mt) {
#pragma unroll
    for (int nt = 0; nt < 4; ++nt) {
#pragma unroll
      for (int r = 0; r < 4; ++r) {
        const int gm = m0 + wm + mt * 16 + quad * 4 + r;  // token
        const int gn = n0 + wn + nt * 16 + l15;           // 0..3071
        float v = acc[mt][nt][r];
        const int wsel = gn >> 10;      // 0=Q 1=K 2=V
        const int n = gn & 1023;
        const int h = n >> 6, d = n & 63;
        const int b = gm >> 10, i = gm & 1023;
        const size_t bh = (size_t)(b * 16 + h);
        if (wsel == 0) {
          v = (v + bq[n]) * kScale;     // fold softmax scale into Q
          Qh[(bh * 1024 + i) * 64 + d] = f32_to_bf16(v);
        } else if (wsel == 1) {
          v = v + bk[n] + Er[(size_t)(4999 - i) * 64 + d];
          Kh[(bh * 1024 + i) * 64 + d] = f32_to_bf16(v);
        } else {
          v = v + bv[n];
          Vth[(bh * 64 + d) * 1024 + i] = f32_to_bf16(v);
        }
      }
    }
  }
}

// ---------------- out GEMM  out[4096,1024] = Aoh @ Wo^T + b_o ----------------
// 128x64 tile -> 512 blocks (2/CU). 4 waves stacked in M (32 rows each).
// A tile = 128x32 = 512 16B units (2 passes); B tile = 64x32 = 256 units.
__global__ __launch_bounds__(256)
void gemm_out(const unsigned short* __restrict__ A,   // 4096 x 1024
              const unsigned short* __restrict__ Bm,  // 1024 x 1024
              const float* __restrict__ bias,
              float* __restrict__ outf) {
  __shared__ unsigned short As[128 * 32];
  __shared__ unsigned short Bs[64 * 32];
  const int tid  = threadIdx.x;
  const int lane = tid & 63, wave = tid >> 6;
  const int quad = lane >> 4, l15 = lane & 15;
  const int m0 = blockIdx.y * 128, n0 = blockIdx.x * 64;
  const int K = 1024;

  const f32x4 vzero = {0.f, 0.f, 0.f, 0.f};
  f32x4 acc[2][4];
#pragma unroll
  for (int i = 0; i < 2; ++i)
#pragma unroll
    for (int j = 0; j < 4; ++j) acc[i][j] = vzero;

  for (int k0 = 0; k0 < K; k0 += 32) {
    __syncthreads();
#pragma unroll
    for (int r = 0; r < 2; ++r) {       // A: 512 units
      int u = r * 256 + tid;
      int row = u >> 2, col = (u & 3) * 8;
      gload_lds16(A + (size_t)(m0 + row) * K + k0 + col, (char*)As + (size_t)u * 16);
    }
    {                                   // B: 256 units (64 rows x 32)
      int u = tid;
      int row = u >> 2, col = (u & 3) * 8;
      gload_lds16(Bm + (size_t)(n0 + row) * K + k0 + col, (char*)Bs + (size_t)u * 16);
    }
    __syncthreads();

    short8 af[2], bfv[4];
#pragma unroll
    for (int mt = 0; mt < 2; ++mt)
      af[mt] = *(const short8*)&As[(wave * 32 + mt * 16 + l15) * 32 + quad * 8];
#pragma unroll
    for (int nt = 0; nt < 4; ++nt)
      bfv[nt] = *(const short8*)&Bs[(nt * 16 + l15) * 32 + quad * 8];
#pragma unroll
    for (int mt = 0; mt < 2; ++mt)
#pragma unroll
      for (int nt = 0; nt < 4; ++nt)
        acc[mt][nt] = MFMA_BF16(af[mt], bfv[nt], acc[mt][nt]);
  }

#pragma unroll
  for (int mt = 0; mt < 2; ++mt)
#pragma unroll
    for (int nt = 0; nt < 4; ++nt)
#pragma unroll
      for (int r = 0; r < 4; ++r) {
        const int gm = m0 + wave * 32 + mt * 16 + quad * 4 + r;
        const int gn = n0 + nt * 16 + l15;
        outf[(size_t)gm * 1024 + gn] = acc[mt][nt][r] + bias[gn];
      }
}

// ---------------- flash attention, LDS-staged K/V, prefetch ----------------
// grid (64 bh, 8 qblocks of 128), 256 threads. Wave owns 32 query rows.
// Q pre-scaled by log2(e)/8; no-max softmax (exp2 cannot overflow here).
// K/V tiles stored as two BK=32 halves -> 64B LDS rows (2-way bank alias, free).
__global__ __launch_bounds__(256)
void attn_kernel(const unsigned short* __restrict__ Q,
                 const unsigned short* __restrict__ Kp,
                 const unsigned short* __restrict__ Vt,
                 unsigned short* __restrict__ Ao) {
  __shared__ unsigned short Ks[2][2][64 * 32];  // [buf][half][key][32]
  __shared__ unsigned short Vs[2][2][64 * 32];  // [buf][half][d][32]
  __shared__ unsigned short Plds[4][32 * 72];   // per-wave P transpose
  const int tid  = threadIdx.x;
  const int lane = tid & 63, wave = tid >> 6;
  const int quad = lane >> 4, l15 = lane & 15;
  const int bh = blockIdx.x;
  const int qb = blockIdx.y;
  const size_t base  = (size_t)bh * (kL * 64);
  const size_t vbase = (size_t)bh * (64 * kL);
  const int i0 = qb * 128 + wave * 32;

  // Q fragments: 2 m-tiles x 2 k-steps, held in regs for whole kernel
  short8 qf[2][2];
#pragma unroll
  for (int mt = 0; mt < 2; ++mt)
#pragma unroll
    for (int ks = 0; ks < 2; ++ks)
      qf[mt][ks] = *(const short8*)
          &Q[base + (size_t)(i0 + mt * 16 + l15) * 64 + ks * 32 + quad * 8];

  // stage K/V tile kb into buffer buf. unit u in [0,512): LDS elem = u*8
  //  -> half = u>>8, row = (u>>2)&63, c = (u&3)*8   (lane-contiguous 16B)
  auto stage = [&](int buf, int kb) {
#pragma unroll
    for (int j = 0; j < 2; ++j) {
      int u = j * 256 + tid;
      int half = u >> 8, row = (u >> 2) & 63, c = (u & 3) * 8;
      gload_lds16(Kp + base + (size_t)(kb * 64 + row) * 64 + half * 32 + c,
                  (char*)&Ks[buf][0][0] + (size_t)u * 16);
      gload_lds16(Vt + vbase + (size_t)row * kL + kb * 64 + half * 32 + c,
                  (char*)&Vs[buf][0][0] + (size_t)u * 16);
    }
  };

  const f32x4 vzero = {0.f, 0.f, 0.f, 0.f};
  f32x4 of[2][4];
#pragma unroll
  for (int mt = 0; mt < 2; ++mt)
#pragma unroll
    for (int dt = 0; dt < 4; ++dt) of[mt][dt] = vzero;
  float lsum[2][4] = {{0.f, 0.f, 0.f, 0.f}, {0.f, 0.f, 0.f, 0.f}};

  unsigned short* Pw = Plds[wave];

  stage(0, 0);
  __syncthreads();   // drains vmcnt -> tile 0 visible

  for (int kb = 0; kb < 16; ++kb) {
    const int cur = kb & 1, nxt = cur ^ 1;
    if (kb < 15) stage(nxt, kb + 1);   // async; lands before end-of-iter barrier

    // ---- S = Q @ K'^T (64 keys) ----
    short8 kf[4][2];
#pragma unroll
    for (int nt = 0; nt < 4; ++nt)
#pragma unroll
      for (int ks = 0; ks < 2; ++ks)
        kf[nt][ks] = *(const short8*)&Ks[cur][ks][(nt * 16 + l15) * 32 + quad * 8];
    f32x4 sf[2][4];
#pragma unroll
    for (int mt = 0; mt < 2; ++mt)
#pragma unroll
      for (int nt = 0; nt < 4; ++nt) {
        sf[mt][nt] = MFMA_BF16(qf[mt][0], kf[nt][0], vzero);
        sf[mt][nt] = MFMA_BF16(qf[mt][1], kf[nt][1], sf[mt][nt]);
      }

    // ---- P = exp2(S); partial row sums; transpose via wave-private LDS ----
#pragma unroll
    for (int mt = 0; mt < 2; ++mt)
#pragma unroll
      for (int nt = 0; nt < 4; ++nt)
#pragma unroll
        for (int r = 0; r < 4; ++r) {
          float p = __builtin_amdgcn_exp2f(sf[mt][nt][r]);
          lsum[mt][r] += p;
          union { float f; uint32_t u; } c; c.f = p;
          Pw[(mt * 16 + quad * 4 + r) * 72 + nt * 16 + l15] =
              (unsigned short)((c.u + 0x8000u) >> 16);   // RN pack, 1 add
        }
    short8 pf[2][2];
#pragma unroll
    for (int mt = 0; mt < 2; ++mt)
#pragma unroll
      for (int ks = 0; ks < 2; ++ks)
        pf[mt][ks] = *(const short8*)&Pw[(mt * 16 + l15) * 72 + ks * 32 + quad * 8];

    // ---- O += P @ V ----
    short8 vf[4][2];
#pragma unroll
    for (int dt = 0; dt < 4; ++dt)
#pragma unroll
      for (int ks = 0; ks < 2; ++ks)
        vf[dt][ks] = *(const short8*)&Vs[cur][ks][(dt * 16 + l15) * 32 + quad * 8];
#pragma unroll
    for (int mt = 0; mt < 2; ++mt)
#pragma unroll
      for (int dt = 0; dt < 4; ++dt) {
        of[mt][dt] = MFMA_BF16(pf[mt][0], vf[dt][0], of[mt][dt]);
        of[mt][dt] = MFMA_BF16(pf[mt][1], vf[dt][1], of[mt][dt]);
      }

    __syncthreads();  // prefetch landed + all waves done with cur buffer
  }

  // ---- finish row sums across 16 lanes ----
#pragma unroll
  for (int mask = 1; mask < 16; mask <<= 1)
#pragma unroll
    for (int mt = 0; mt < 2; ++mt)
#pragma unroll
      for (int r = 0; r < 4; ++r)
        lsum[mt][r] += __shfl_xor(lsum[mt][r], mask);
  float rl[2][4];
#pragma unroll
  for (int mt = 0; mt < 2; ++mt)
#pragma unroll
    for (int r = 0; r < 4; ++r) rl[mt][r] = __builtin_amdgcn_rcpf(lsum[mt][r]);

  // ---- write Ao[b*L + i][h*64 + d] (bf16) ----
  const int b = bh >> 4, h = bh & 15;
#pragma unroll
  for (int mt = 0; mt < 2; ++mt)
#pragma unroll
    for (int dt = 0; dt < 4; ++dt)
#pragma unroll
      for (int r = 0; r < 4; ++r) {
        const int ig = i0 + mt * 16 + quad * 4 + r;
        float v = of[mt][dt][r] * rl[mt][r];
        Ao[((size_t)(b * 1024 + ig)) * 1024 + h * 64 + dt * 16 + l15] = f32_to_bf16(v);
      }
}

// ---------------------------------------------------------------------------
extern "C" void kernel_launch(void* const* d_in, const int* in_sizes, int n_in,
                              void* d_out, int out_size, void* d_ws, size_t ws_size,
                              hipStream_t stream) {
  const float* x   = (const float*)d_in[0];
  const float* W_q = (const float*)d_in[1];
  const float* b_q = (const float*)d_in[2];
  const float* W_k = (const float*)d_in[3];
  const float* b_k = (const float*)d_in[4];
  const float* W_v = (const float*)d_in[5];
  const float* b_v = (const float*)d_in[6];
  const float* W_o = (const float*)d_in[7];
  const float* b_o = (const float*)d_in[8];
  const float* Er  = (const float*)d_in[9];
  float* out = (float*)d_out;

  char* ws = (char*)d_ws;
  unsigned short* xb   = (unsigned short*)(ws + (size_t)0);          // 8 MB
  unsigned short* Wcat = (unsigned short*)(ws + ((size_t)8  << 20)); // 6 MB (Wq|Wk|Wv)
  unsigned short* Wob  = (unsigned short*)(ws + ((size_t)14 << 20)); // 2 MB
  unsigned short* Qh   = (unsigned short*)(ws + ((size_t)16 << 20)); // 8 MB [bh][i][d]
  unsigned short* Kh   = (unsigned short*)(ws + ((size_t)24 << 20)); // 8 MB [bh][i][d]
  unsigned short* Vth  = (unsigned short*)(ws + ((size_t)32 << 20)); // 8 MB [bh][d][i]
  unsigned short* Aoh  = (unsigned short*)(ws + ((size_t)40 << 20)); // 8 MB [b*L][D]

  cast_all<<<8192, 256, 0, stream>>>(x, W_q, W_k, W_v, W_o, xb, Wcat, Wob);

  gemm_qkv<<<dim3(24, 32), 256, 0, stream>>>(
      xb, Wcat, b_q, b_k, b_v, Er, Qh, Kh, Vth);

  attn_kernel<<<dim3(kB * kH, kL / 128), 256, 0, stream>>>(Qh, Kh, Vth, Aoh);

  gemm_out<<<dim3(16, 32), 256, 0, stream>>>(Aoh, Wob, b_o, out);
}